// Round 4
// baseline (904.078 us; speedup 1.0000x reference)
//
#include <hip/hip_runtime.h>
#include <hip/hip_bf16.h>

typedef __attribute__((ext_vector_type(8))) short bf16x8;
typedef __attribute__((ext_vector_type(4))) float f32x4;
typedef __attribute__((ext_vector_type(8))) unsigned short us8;

#define MFMA16(a, b, c) __builtin_amdgcn_mfma_f32_16x16x32_bf16((a), (b), (c), 0, 0, 0)

// Problem dims (fixed)
static constexpr int Bn = 16;
static constexpr int Nn = 4096;
static constexpr int Cn = 512;
static constexpr int Mn = 32;
static constexpr int NR = Bn * Nn;  // 65536 rows

// workspace layout (bytes)
static constexpr size_t OFF_XBF  = 0;                         // NR*512 bf16 = 67108864
static constexpr size_t OFF_XINV = 67108864;                  // NR f32 = 262144
static constexpr size_t OFF_YN   = OFF_XINV + 262144;         // 512*512 bf16 (normalized y)
static constexpr size_t OFF_YR   = OFF_YN + 524288;           // 512*512 bf16 (raw y)
static constexpr size_t OFF_WT   = OFF_YR + 524288;           // 512*1024 bf16 (W^T)
static constexpr size_t OFF_ZT   = OFF_WT + 1048576;          // 16*512*32 bf16 (Z^T)
static constexpr size_t OFF_CNT  = OFF_ZT + 524288;           // 512 int = 2048
static constexpr size_t OFF_VERR = OFF_CNT + 2048;            // 50*16 f32 = 3200
static constexpr size_t OFF_JS   = OFF_VERR + 3200;           // 256
static constexpr size_t OFF_VTR  = OFF_JS + 256;              // 50*512 f32 = 102400
static constexpr size_t OFF_K    = OFF_VTR + 102400;          // NR*32 f32 = 8388608
static constexpr size_t OFF_PIN  = OFF_K + 8388608;           // NR*32 bf16 = 4194304

__device__ __forceinline__ unsigned short f2bf(float f) {
  union { float f; unsigned u; } x; x.f = f;
  return (unsigned short)((x.u + 0x7FFFu + ((x.u >> 16) & 1u)) >> 16);
}
__device__ __forceinline__ float bf2f(unsigned short h) {
  union { unsigned u; float f; } x; x.u = ((unsigned)h) << 16;
  return x.f;
}
// packed-bf16 unpack: lo element = bits[15:0], hi element = bits[31:16]
__device__ __forceinline__ float bflo(unsigned u) {
  union { unsigned v; float f; } x; x.v = u << 16; return x.f;
}
__device__ __forceinline__ float bfhi(unsigned u) {
  union { unsigned v; float f; } x; x.v = u & 0xFFFF0000u; return x.f;
}

// ---------------- init: zero accumulators ----------------
__global__ void k_init(int* __restrict__ cnts, float* __restrict__ ot) {
  int t = threadIdx.x;
  if (t < 512) cnts[t] = 0;
  if (t < 16) ot[t] = 0.f;
}

// ---------------- x prep: rownorm + bf16 convert ----------------
__global__ __launch_bounds__(256) void k_xprep(const float* __restrict__ x,
                                               unsigned short* __restrict__ xbf,
                                               float* __restrict__ xinv) {
  int wid = threadIdx.x >> 6, l = threadIdx.x & 63;
  int row = blockIdx.x * 4 + wid;
  const float4* p = (const float4*)(x + (size_t)row * Cn);
  float4 a0 = p[l];
  float4 a1 = p[64 + l];
  float s = a0.x*a0.x + a0.y*a0.y + a0.z*a0.z + a0.w*a0.w
          + a1.x*a1.x + a1.y*a1.y + a1.z*a1.z + a1.w*a1.w;
  #pragma unroll
  for (int d = 1; d < 64; d <<= 1) s += __shfl_xor(s, d, 64);
  ushort4 o0, o1;
  o0.x = f2bf(a0.x); o0.y = f2bf(a0.y); o0.z = f2bf(a0.z); o0.w = f2bf(a0.w);
  o1.x = f2bf(a1.x); o1.y = f2bf(a1.y); o1.z = f2bf(a1.z); o1.w = f2bf(a1.w);
  ushort4* q = (ushort4*)(xbf + (size_t)row * Cn);
  q[l] = o0; q[64 + l] = o1;
  if (l == 0) xinv[row] = rsqrtf(s);
}

// ---------------- y prep: normalized + raw bf16 ----------------
__global__ __launch_bounds__(256) void k_ynorm(const float* __restrict__ y,
                                               unsigned short* __restrict__ ynbf,
                                               unsigned short* __restrict__ yrbf) {
  int wid = threadIdx.x >> 6, l = threadIdx.x & 63;
  int row = blockIdx.x * 4 + wid;  // 0..511
  const float4* p = (const float4*)(y + (size_t)row * Cn);
  float4 a0 = p[l];
  float4 a1 = p[64 + l];
  float s = a0.x*a0.x + a0.y*a0.y + a0.z*a0.z + a0.w*a0.w
          + a1.x*a1.x + a1.y*a1.y + a1.z*a1.z + a1.w*a1.w;
  #pragma unroll
  for (int d = 1; d < 64; d <<= 1) s += __shfl_xor(s, d, 64);
  float inv = rsqrtf(s);
  ushort4 r0, r1, n0, n1;
  r0.x = f2bf(a0.x); r0.y = f2bf(a0.y); r0.z = f2bf(a0.z); r0.w = f2bf(a0.w);
  r1.x = f2bf(a1.x); r1.y = f2bf(a1.y); r1.z = f2bf(a1.z); r1.w = f2bf(a1.w);
  n0.x = f2bf(a0.x*inv); n0.y = f2bf(a0.y*inv); n0.z = f2bf(a0.z*inv); n0.w = f2bf(a0.w*inv);
  n1.x = f2bf(a1.x*inv); n1.y = f2bf(a1.y*inv); n1.z = f2bf(a1.z*inv); n1.w = f2bf(a1.w*inv);
  ushort4* qr = (ushort4*)(yrbf + (size_t)row * Cn);
  ushort4* qn = (ushort4*)(ynbf + (size_t)row * Cn);
  qr[l] = r0; qr[64 + l] = r1;
  qn[l] = n0; qn[64 + l] = n1;
}

// ---------------- nu: argmax counts ----------------
__global__ __launch_bounds__(256) void k_nu(const float* __restrict__ sm, int* __restrict__ cnts) {
  int g = blockIdx.x * 256 + threadIdx.x;
  int b = g >> 12, p = g & 4095;
  const float* base = sm + (size_t)b * Mn * Nn;
  float best = base[p];
  int bi = 0;
  #pragma unroll 4
  for (int k = 1; k < Mn; k++) {
    float v = base[(size_t)k * Nn + p];
    if (v > best) { best = v; bi = k; }
  }
  __shared__ int lc[Mn];
  if (threadIdx.x < Mn) lc[threadIdx.x] = 0;
  __syncthreads();
  atomicAdd(&lc[bi], 1);
  __syncthreads();
  if (threadIdx.x < Mn) atomicAdd(&cnts[b * Mn + threadIdx.x], lc[threadIdx.x]);
}

// ---------------- W transpose -> bf16 : WT[n][k], k in [0,1024) ----------------
__global__ __launch_bounds__(256) void k_wt(const float* __restrict__ w, unsigned short* __restrict__ wt) {
  __shared__ float tile[32][33];
  int k0 = blockIdx.x * 32;
  int n0 = blockIdx.y * 32;
  int tx = threadIdx.x & 31, ty = threadIdx.x >> 5;
  #pragma unroll
  for (int i = 0; i < 4; i++) tile[ty + 8*i][tx] = w[(size_t)(k0 + ty + 8*i) * 512 + n0 + tx];
  __syncthreads();
  #pragma unroll
  for (int i = 0; i < 4; i++)
    wt[(size_t)(n0 + ty + 8*i) * 1024 + k0 + tx] = f2bf(tile[tx][ty + 8*i]);
}

// ---------------- Z^T = (y @ W_bot)^T, bf16, layout [b][n(512)][m(32)] ----------------
__global__ __launch_bounds__(256) void k_zt(const unsigned short* __restrict__ yraw,
                                            const unsigned short* __restrict__ wt,
                                            unsigned short* __restrict__ zt) {
  int wv = blockIdx.x * 4 + (threadIdx.x >> 6);
  int l = threadIdx.x & 63;
  int b = wv >> 6, rem = wv & 63, mt = rem >> 5, nt = rem & 31;
  int kg = l >> 4;
  const unsigned short* ap = yraw + ((size_t)(b * 32 + mt * 16 + (l & 15)) * 512 + kg * 8);
  const unsigned short* bp = wt + ((size_t)(nt * 16 + (l & 15)) * 1024 + 512 + kg * 8);
  f32x4 acc = {0.f, 0.f, 0.f, 0.f};
  #pragma unroll
  for (int ks = 0; ks < 16; ks++) {
    bf16x8 a = *(const bf16x8*)(ap + ks * 32);
    bf16x8 bb = *(const bf16x8*)(bp + ks * 32);
    acc = MFMA16(a, bb, acc);
  }
  int n = nt * 16 + (l & 15);
  #pragma unroll
  for (int r = 0; r < 4; r++) {
    int m = mt * 16 + kg * 4 + r;
    zt[((size_t)b * 512 + n) * 32 + m] = f2bf(acc[r]);
  }
}

// ---------------- K matrix: Kmat = exp(-20*(1 - xn.yn)), f32 row-major ----------------
__global__ __launch_bounds__(256) void k_cost(const unsigned short* __restrict__ xbf,
                                              const float* __restrict__ xinv,
                                              const unsigned short* __restrict__ ynbf,
                                              float* __restrict__ kmat) {
  int wv = blockIdx.x * 4 + (threadIdx.x >> 6);  // 0..4095 row-tiles of 16
  int l = threadIdx.x & 63;
  int r0 = wv * 16;
  int b = r0 >> 12;
  int kg = l >> 4;
  const unsigned short* ap = xbf + ((size_t)(r0 + (l & 15)) * 512 + kg * 8);
  const unsigned short* b0p = ynbf + ((size_t)(b * 32 + (l & 15)) * 512 + kg * 8);
  const unsigned short* b1p = ynbf + ((size_t)(b * 32 + 16 + (l & 15)) * 512 + kg * 8);
  f32x4 acc0 = {0.f, 0.f, 0.f, 0.f}, acc1 = {0.f, 0.f, 0.f, 0.f};
  #pragma unroll
  for (int ks = 0; ks < 16; ks++) {
    bf16x8 a = *(const bf16x8*)(ap + ks * 32);
    acc0 = MFMA16(a, *(const bf16x8*)(b0p + ks * 32), acc0);
    acc1 = MFMA16(a, *(const bf16x8*)(b1p + ks * 32), acc1);
  }
  int col = l & 15;
  #pragma unroll
  for (int r = 0; r < 4; r++) {
    int row = r0 + kg * 4 + r;
    float inv = xinv[row];
    kmat[(size_t)row * 32 + col]      = __expf(-20.f * (1.f - acc0[r] * inv));
    kmat[(size_t)row * 32 + col + 16] = __expf(-20.f * (1.f - acc1[r] * inv));
  }
}

// ---------------- Sinkhorn: 16 blocks (one per batch), 1024 threads, K in VGPRs ----------------
// Round-3's proven spill-free register structure (kq[64], chunked cacc[16]x2, live ~116)
// at 1024 threads (16 waves = 4/SIMD, 128-VGPR budget). Entire iteration is
// register+LDS only: no cross-block exchange, no global traffic in the loop.
__global__ __launch_bounds__(1024, 4) void k_sink1(const float* __restrict__ kmat,
                                                   const int* __restrict__ cnts,
                                                   float* __restrict__ verr,
                                                   float* __restrict__ vtrace) {
  int b = blockIdx.x;   // 0..15
  int t = threadIdx.x;  // 0..1023
  int lane = t & 63;
  int w = t >> 6;       // wave 0..15
  __shared__ float v_s[32], nu_s[32];
  __shared__ float red_s[16];
  __shared__ float cred[16][32];
  __shared__ float vhist[50][32];
  __shared__ float ehist[50];
  __shared__ float errtot_s;
  if (t < 32) {
    float c = (float)cnts[b * 32 + t];
    float nu = c / (4096.f + 1e-8f) + 1e-6f;
    float ss = nu;
    #pragma unroll
    for (int d = 1; d < 32; d <<= 1) ss += __shfl_xor(ss, d, 64);
    nu_s[t] = nu / ss;
    v_s[t] = 0.f;
  }
  // one-time load of this thread's 4 rows of K, packed to bf16 pairs (64 VGPRs)
  unsigned kq[64];
  {
    const float4* kp = (const float4*)(kmat + ((size_t)b * 4096 + (size_t)t * 4) * 32);
    #pragma unroll
    for (int r = 0; r < 4; r++) {
      #pragma unroll
      for (int q = 0; q < 8; q++) {
        float4 kv = kp[r * 8 + q];
        kq[r * 16 + q * 2]     = (unsigned)f2bf(kv.x) | ((unsigned)f2bf(kv.y) << 16);
        kq[r * 16 + q * 2 + 1] = (unsigned)f2bf(kv.z) | ((unsigned)f2bf(kv.w) << 16);
      }
    }
  }
  float uprev[4] = {0.f, 0.f, 0.f, 0.f};
  __syncthreads();

  for (int iter = 0; iter < 50; iter++) {
    // ---- u-pass: rows 4t..4t+3, v broadcast from LDS ----
    float accA[4] = {0.f, 0.f, 0.f, 0.f}, accB[4] = {0.f, 0.f, 0.f, 0.f};
    {
      const float4* v4 = (const float4*)v_s;
      #pragma unroll
      for (int j = 0; j < 8; j++) {
        float4 vv = v4[j];
        #pragma unroll
        for (int hh = 0; hh < 2; hh++) {
          int q = j * 2 + hh;
          float va = hh ? vv.z : vv.x;
          float vb = hh ? vv.w : vv.y;
          #pragma unroll
          for (int r = 0; r < 4; r++) {
            unsigned pk = kq[r * 16 + q];
            accA[r] += bflo(pk) * va;
            accB[r] += bfhi(pk) * vb;
          }
        }
      }
    }
    float un[4];
    float errloc = 0.f;
    #pragma unroll
    for (int r = 0; r < 4; r++) {
      un[r] = (1.0f/4096.f) / (accA[r] + accB[r] + 1e-8f);
      errloc += fabsf(un[r] - uprev[r]);
      uprev[r] = un[r];
    }
    #pragma unroll
    for (int d = 1; d < 64; d <<= 1) errloc += __shfl_xor(errloc, d, 64);
    if (lane == 0) red_s[w] = errloc;

    // ---- v-pass partials, 2 chunks of 16 cols (keeps live regs low) ----
    #define FOLD(MASK, HALF)                                        \
    {                                                               \
      bool up_ = (lane & (MASK)) != 0;                              \
      _Pragma("unroll")                                             \
      for (int i = 0; i < (HALF); i++) {                            \
        float s_ = up_ ? cacc[i] : cacc[i + (HALF)];                \
        float r_ = __shfl_xor(s_, (MASK), 64);                      \
        cacc[i] = (up_ ? cacc[i + (HALF)] : cacc[i]) + r_;          \
      }                                                             \
    }
    #pragma unroll
    for (int ch = 0; ch < 2; ch++) {
      float cacc[16];
      #pragma unroll
      for (int c = 0; c < 16; c++) cacc[c] = 0.f;
      #pragma unroll
      for (int qq = 0; qq < 8; qq++) {
        int q = ch * 8 + qq;
        #pragma unroll
        for (int r = 0; r < 4; r++) {
          unsigned pk = kq[r * 16 + q];
          cacc[2*qq]   += bflo(pk) * un[r];
          cacc[2*qq+1] += bfhi(pk) * un[r];
        }
      }
      FOLD(1, 8)
      FOLD(2, 4)
      FOLD(4, 2)
      FOLD(8, 1)
      cacc[0] += __shfl_xor(cacc[0], 16, 64);
      cacc[0] += __shfl_xor(cacc[0], 32, 64);
      int col4 = ((lane & 1) << 3) | ((lane & 2) << 1) | ((lane & 4) >> 1) | ((lane & 8) >> 3);
      if (lane < 16) cred[w][ch * 16 + col4] = cacc[0];
    }
    #undef FOLD
    __syncthreads();  // A: cred/red_s ready

    // ---- wave 0: second-stage reduce + v update (all in LDS) ----
    if (w == 0) {
      float sumP = 0.f, errP = 0.f;
      if (lane < 32) {
        #pragma unroll
        for (int ww = 0; ww < 16; ww++) sumP += cred[ww][lane];
      }
      if (lane == 0) {
        #pragma unroll
        for (int ww = 0; ww < 16; ww++) errP += red_s[ww];
        errtot_s = errP;
        ehist[iter] = errP;
      }
      if (lane < 32) {
        float v = nu_s[lane] / (sumP + 1e-8f);
        v_s[lane] = v;
        vhist[iter][lane] = v;
      }
    }
    __syncthreads();  // B: v_s/errtot_s ready
    if (errtot_s == 0.0f) {
      // fp32 fixpoint: all further iterations identical — fill and stop
      if (t < 32) {
        float vv = v_s[t];
        for (int k = iter; k < 50; k++) vhist[k][t] = vv;
        if (t == 0) for (int k = iter; k < 50; k++) ehist[k] = 0.f;
      }
      break;
    }
  }

  // ---- dump histories to global (once) ----
  __syncthreads();
  for (int idx = t; idx < 1600; idx += 1024) {
    int k = idx >> 5, m = idx & 31;
    vtrace[k * 512 + b * 32 + m] = vhist[k][m];
  }
  if (t < 50) verr[t * 16 + b] = ehist[t];
}

// ---------------- stop iteration: first iter with batch-mean err < 0.1 ----------------
__global__ void k_stop(const float* __restrict__ verr, int* __restrict__ jstar) {
  int t = threadIdx.x;
  float m = 1e30f;
  if (t < 50) {
    float s = 0.f;
    #pragma unroll
    for (int b2 = 0; b2 < 16; b2++) s += verr[t * 16 + b2];
    m = s * (1.f / 16.f);
  }
  unsigned long long mask = __ballot(m < 0.1f);
  if (t == 0) *jstar = mask ? (int)(__ffsll(mask) - 1) : 49;
}

// ---------------- pi, pi_norm (bf16), ot ----------------
__global__ __launch_bounds__(256) void k_pi(const float* __restrict__ kmat,
                                            const float* __restrict__ vtrace,
                                            const int* __restrict__ jstar,
                                            unsigned short* __restrict__ pinbf,
                                            float* __restrict__ piout,
                                            float* __restrict__ otout) {
  int gr = blockIdx.x * 256 + threadIdx.x;  // row 0..65535 (block never straddles a batch)
  int b = gr >> 12;
  __shared__ float vp_s[32], vc_s[32];
  __shared__ float red[4];
  if (threadIdx.x < 32) {
    int j = *jstar;
    vp_s[threadIdx.x] = (j == 0) ? 0.f : vtrace[(j - 1) * 512 + b * 32 + threadIdx.x];
    vc_s[threadIdx.x] = vtrace[j * 512 + b * 32 + threadIdx.x];
  }
  __syncthreads();
  const float4* kp = (const float4*)(kmat + (size_t)gr * 32);
  float4 K4[8];
  #pragma unroll
  for (int q = 0; q < 8; q++) K4[q] = kp[q];
  float qd = 0.f;
  #pragma unroll
  for (int q = 0; q < 8; q++)
    qd += K4[q].x * vp_s[q*4] + K4[q].y * vp_s[q*4+1] + K4[q].z * vp_s[q*4+2] + K4[q].w * vp_s[q*4+3];
  float u = (1.0f/4096.f) / (qd + 1e-8f);
  float pi[32];
  float s = 0.f, ot = 0.f;
  #pragma unroll
  for (int q = 0; q < 8; q++) {
    float kv[4] = {K4[q].x, K4[q].y, K4[q].z, K4[q].w};
    #pragma unroll
    for (int r = 0; r < 4; r++) {
      int m = q * 4 + r;
      float p = u * kv[r] * vc_s[m];
      pi[m] = p;
      s += p;
      ot += p * (-0.05f * __logf(kv[r]));
    }
  }
  float inv = 1.0f / (s + 1e-8f);
  float4* po = (float4*)(piout + (size_t)gr * 32);
  #pragma unroll
  for (int q = 0; q < 8; q++) {
    float4 w; w.x = pi[q*4]; w.y = pi[q*4+1]; w.z = pi[q*4+2]; w.w = pi[q*4+3];
    po[q] = w;
  }
  us8* pb = (us8*)(pinbf + (size_t)gr * 32);
  #pragma unroll
  for (int q = 0; q < 4; q++) {
    us8 v8;
    #pragma unroll
    for (int r = 0; r < 8; r++) v8[r] = f2bf(pi[q*8+r] * inv);
    pb[q] = v8;
  }
  #pragma unroll
  for (int d = 1; d < 64; d <<= 1) ot += __shfl_xor(ot, d, 64);
  if ((threadIdx.x & 63) == 0) red[threadIdx.x >> 6] = ot;
  __syncthreads();
  if (threadIdx.x == 0) atomicAdd(&otout[b], red[0] + red[1] + red[2] + red[3]);
}

// ---------------- Fusion GEMM + LN: out = LN(x@Wtop + pin@Z + bias) ----------------
__global__ __launch_bounds__(256, 2) void k_fusion(const unsigned short* __restrict__ xbf,
                                                   const unsigned short* __restrict__ pinbf,
                                                   const unsigned short* __restrict__ wt,
                                                   const unsigned short* __restrict__ zt,
                                                   const float* __restrict__ bias,
                                                   const float* __restrict__ gamma,
                                                   const float* __restrict__ beta_,
                                                   float* __restrict__ out) {
  int t = threadIdx.x;
  int wid = t >> 6, l = t & 63;
  int row0 = blockIdx.x * 64;
  int b = row0 >> 12;
  int col0 = wid * 128;
  int m16 = l & 15, kg = l >> 4;
  f32x4 acc[4][8];
  #pragma unroll
  for (int rt = 0; rt < 4; rt++)
    #pragma unroll
    for (int ct = 0; ct < 8; ct++) acc[rt][ct] = (f32x4){0.f, 0.f, 0.f, 0.f};

  const unsigned short* aB[4];
  const unsigned short* bB[8];
  #pragma unroll
  for (int rt = 0; rt < 4; rt++) aB[rt] = xbf + ((size_t)(row0 + rt * 16 + m16) * 512 + kg * 8);
  #pragma unroll
  for (int ct = 0; ct < 8; ct++) bB[ct] = wt + ((size_t)(col0 + ct * 16 + m16) * 1024 + kg * 8);

  for (int ks = 0; ks < 16; ks++) {
    bf16x8 A[4], Bf[8];
    #pragma unroll
    for (int rt = 0; rt < 4; rt++) A[rt] = *(const bf16x8*)(aB[rt] + ks * 32);
    #pragma unroll
    for (int ct = 0; ct < 8; ct++) Bf[ct] = *(const bf16x8*)(bB[ct] + ks * 32);
    #pragma unroll
    for (int rt = 0; rt < 4; rt++)
      #pragma unroll
      for (int ct = 0; ct < 8; ct++) acc[rt][ct] = MFMA16(A[rt], Bf[ct], acc[rt][ct]);
  }
  {  // pi_norm @ Z chunk (K=32)
    bf16x8 A[4], Bf[8];
    #pragma unroll
    for (int rt = 0; rt < 4; rt++)
      A[rt] = *(const bf16x8*)(pinbf + (size_t)(row0 + rt * 16 + m16) * 32 + kg * 8);
    #pragma unroll
    for (int ct = 0; ct < 8; ct++)
      Bf[ct] = *(const bf16x8*)(zt + ((size_t)(b * 512 + col0 + ct * 16 + m16)) * 32 + kg * 8);
    #pragma unroll
    for (int rt = 0; rt < 4; rt++)
      #pragma unroll
      for (int ct = 0; ct < 8; ct++) acc[rt][ct] = MFMA16(A[rt], Bf[ct], acc[rt][ct]);
  }
  float bi[8], ga[8], be[8];
  #pragma unroll
  for (int ct = 0; ct < 8; ct++) {
    int c = col0 + ct * 16 + m16;
    bi[ct] = bias[c]; ga[ct] = gamma[c]; be[ct] = beta_[c];
  }
  __shared__ float p1[4][64], p2[4][64];
  #pragma unroll
  for (int rt = 0; rt < 4; rt++) {
    #pragma unroll
    for (int r = 0; r < 4; r++) {
      float s1 = 0.f, s2 = 0.f;
      #pragma unroll
      for (int ct = 0; ct < 8; ct++) {
        float val = acc[rt][ct][r] + bi[ct];
        s1 += val; s2 += val * val;
      }
      #pragma unroll
      for (int d = 1; d < 16; d <<= 1) {
        s1 += __shfl_xor(s1, d, 64);
        s2 += __shfl_xor(s2, d, 64);
      }
      if (m16 == 0) {
        int rloc = rt * 16 + kg * 4 + r;
        p1[wid][rloc] = s1; p2[wid][rloc] = s2;
      }
    }
  }
  __syncthreads();
  __shared__ float lnM[64], lnR[64];
  if (t < 64) {
    float s1 = p1[0][t] + p1[1][t] + p1[2][t] + p1[3][t];
    float s2 = p2[0][t] + p2[1][t] + p2[2][t] + p2[3][t];
    float mean = s1 * (1.f / 512.f);
    float var = s2 * (1.f / 512.f) - mean * mean;
    lnM[t] = mean;
    lnR[t] = rsqrtf(var + 1e-5f);
  }
  __syncthreads();
  #pragma unroll
  for (int rt = 0; rt < 4; rt++) {
    #pragma unroll
    for (int r = 0; r < 4; r++) {
      int rloc = rt * 16 + kg * 4 + r;
      float mean = lnM[rloc], rst = lnR[rloc];
      #pragma unroll
      for (int ct = 0; ct < 8; ct++) {
        float val = acc[rt][ct][r] + bi[ct];
        out[(size_t)(row0 + rloc) * 512 + col0 + ct * 16 + m16] = (val - mean) * rst * ga[ct] + be[ct];
      }
    }
  }
}

extern "C" void kernel_launch(void* const* d_in, const int* in_sizes, int n_in,
                              void* d_out, int out_size, void* d_ws, size_t ws_size,
                              hipStream_t stream) {
  const float* x  = (const float*)d_in[0];
  const float* y  = (const float*)d_in[1];
  const float* sm = (const float*)d_in[2];
  const float* fw = (const float*)d_in[3];
  const float* fb = (const float*)d_in[4];
  const float* g  = (const float*)d_in[5];
  const float* be = (const float*)d_in[6];

  char* ws = (char*)d_ws;
  unsigned short* xbf   = (unsigned short*)(ws + OFF_XBF);
  float*          xinv  = (float*)(ws + OFF_XINV);
  unsigned short* ynbf  = (unsigned short*)(ws + OFF_YN);
  unsigned short* yrbf  = (unsigned short*)(ws + OFF_YR);
  unsigned short* wtbf  = (unsigned short*)(ws + OFF_WT);
  unsigned short* ztbf  = (unsigned short*)(ws + OFF_ZT);
  int*            cnts  = (int*)(ws + OFF_CNT);
  float*          verr  = (float*)(ws + OFF_VERR);
  int*            jst   = (int*)(ws + OFF_JS);
  float*          vtr   = (float*)(ws + OFF_VTR);
  float*          kmat  = (float*)(ws + OFF_K);
  unsigned short* pinbf = (unsigned short*)(ws + OFF_PIN);

  float* outp = (float*)d_out;
  float* otp  = outp + (size_t)Bn * Nn * Cn;
  float* pip  = otp + Bn;

  hipLaunchKernelGGL(k_init, dim3(1), dim3(512), 0, stream, cnts, otp);
  hipLaunchKernelGGL(k_xprep, dim3(NR / 4), dim3(256), 0, stream, x, xbf, xinv);
  hipLaunchKernelGGL(k_ynorm, dim3(128), dim3(256), 0, stream, y, ynbf, yrbf);
  hipLaunchKernelGGL(k_nu, dim3(256), dim3(256), 0, stream, sm, cnts);
  hipLaunchKernelGGL(k_wt, dim3(32, 16), dim3(256), 0, stream, fw, wtbf);
  hipLaunchKernelGGL(k_zt, dim3(256), dim3(256), 0, stream, yrbf, wtbf, ztbf);
  hipLaunchKernelGGL(k_cost, dim3(1024), dim3(256), 0, stream, xbf, xinv, ynbf, kmat);
  hipLaunchKernelGGL(k_sink1, dim3(16), dim3(1024), 0, stream, kmat, cnts, verr, vtr);
  hipLaunchKernelGGL(k_stop, dim3(1), dim3(64), 0, stream, verr, jst);
  hipLaunchKernelGGL(k_pi, dim3(256), dim3(256), 0, stream, kmat, vtr, jst, pinbf, pip, otp);
  hipLaunchKernelGGL(k_fusion, dim3(1024), dim3(256), 0, stream,
                     xbf, pinbf, wtbf, ztbf, fb, g, be, outp);
}

// Round 6
// 599.273 us; speedup vs baseline: 1.5086x; 1.5086x over previous
//
#include <hip/hip_runtime.h>
#include <hip/hip_bf16.h>

typedef __attribute__((ext_vector_type(8))) short bf16x8;
typedef __attribute__((ext_vector_type(4))) float f32x4;
typedef __attribute__((ext_vector_type(8))) unsigned short us8;

#define MFMA16(a, b, c) __builtin_amdgcn_mfma_f32_16x16x32_bf16((a), (b), (c), 0, 0, 0)

// Problem dims (fixed)
static constexpr int Bn = 16;
static constexpr int Nn = 4096;
static constexpr int Cn = 512;
static constexpr int Mn = 32;
static constexpr int NR = Bn * Nn;  // 65536 rows

// workspace layout (bytes)
static constexpr size_t OFF_XBF  = 0;                         // NR*512 bf16 = 67108864
static constexpr size_t OFF_XINV = 67108864;                  // NR f32 = 262144
static constexpr size_t OFF_YN   = OFF_XINV + 262144;         // 512*512 bf16 (normalized y)
static constexpr size_t OFF_YR   = OFF_YN + 524288;           // 512*512 bf16 (raw y)
static constexpr size_t OFF_WT   = OFF_YR + 524288;           // 512*1024 bf16 (W^T)
static constexpr size_t OFF_ZT   = OFF_WT + 1048576;          // 16*512*32 bf16 (Z^T)
static constexpr size_t OFF_CNT  = OFF_ZT + 524288;           // 512 int = 2048
static constexpr size_t OFF_VERR = OFF_CNT + 2048;            // 50*16 f32 = 3200
static constexpr size_t OFF_JS   = OFF_VERR + 3200;           // 256
static constexpr size_t OFF_VTR  = OFF_JS + 256;              // 50*512 f32 = 102400
static constexpr size_t OFF_K    = OFF_VTR + 102400;          // NR*32 f32 = 8388608
static constexpr size_t OFF_PIN  = OFF_K + 8388608;           // NR*32 bf16 = 4194304
// sink-phase sync area ALIASES pinbf (pinbf written only later by k_pi):
//   gflag: 32 ints at OFF_PIN (zeroed by k_init each launch)
//   gpart: 32*2*33 floats at OFF_PIN + 128

__device__ __forceinline__ unsigned short f2bf(float f) {
  union { float f; unsigned u; } x; x.f = f;
  return (unsigned short)((x.u + 0x7FFFu + ((x.u >> 16) & 1u)) >> 16);
}
__device__ __forceinline__ float bf2f(unsigned short h) {
  union { unsigned u; float f; } x; x.u = ((unsigned)h) << 16;
  return x.f;
}
// packed-bf16 unpack: lo element = bits[15:0], hi element = bits[31:16]
__device__ __forceinline__ float bflo(unsigned u) {
  union { unsigned v; float f; } x; x.v = u << 16; return x.f;
}
__device__ __forceinline__ float bfhi(unsigned u) {
  union { unsigned v; float f; } x; x.v = u & 0xFFFF0000u; return x.f;
}

// ---------------- init: zero accumulators + sync flags ----------------
__global__ void k_init(int* __restrict__ cnts, float* __restrict__ ot, int* __restrict__ gflag) {
  int t = threadIdx.x;
  if (t < 512) cnts[t] = 0;
  if (t < 16) ot[t] = 0.f;
  if (t < 32) gflag[t] = 0;
}

// ---------------- x prep: rownorm + bf16 convert ----------------
__global__ __launch_bounds__(256) void k_xprep(const float* __restrict__ x,
                                               unsigned short* __restrict__ xbf,
                                               float* __restrict__ xinv) {
  int wid = threadIdx.x >> 6, l = threadIdx.x & 63;
  int row = blockIdx.x * 4 + wid;
  const float4* p = (const float4*)(x + (size_t)row * Cn);
  float4 a0 = p[l];
  float4 a1 = p[64 + l];
  float s = a0.x*a0.x + a0.y*a0.y + a0.z*a0.z + a0.w*a0.w
          + a1.x*a1.x + a1.y*a1.y + a1.z*a1.z + a1.w*a1.w;
  #pragma unroll
  for (int d = 1; d < 64; d <<= 1) s += __shfl_xor(s, d, 64);
  ushort4 o0, o1;
  o0.x = f2bf(a0.x); o0.y = f2bf(a0.y); o0.z = f2bf(a0.z); o0.w = f2bf(a0.w);
  o1.x = f2bf(a1.x); o1.y = f2bf(a1.y); o1.z = f2bf(a1.z); o1.w = f2bf(a1.w);
  ushort4* q = (ushort4*)(xbf + (size_t)row * Cn);
  q[l] = o0; q[64 + l] = o1;
  if (l == 0) xinv[row] = rsqrtf(s);
}

// ---------------- y prep: normalized + raw bf16 ----------------
__global__ __launch_bounds__(256) void k_ynorm(const float* __restrict__ y,
                                               unsigned short* __restrict__ ynbf,
                                               unsigned short* __restrict__ yrbf) {
  int wid = threadIdx.x >> 6, l = threadIdx.x & 63;
  int row = blockIdx.x * 4 + wid;  // 0..511
  const float4* p = (const float4*)(y + (size_t)row * Cn);
  float4 a0 = p[l];
  float4 a1 = p[64 + l];
  float s = a0.x*a0.x + a0.y*a0.y + a0.z*a0.z + a0.w*a0.w
          + a1.x*a1.x + a1.y*a1.y + a1.z*a1.z + a1.w*a1.w;
  #pragma unroll
  for (int d = 1; d < 64; d <<= 1) s += __shfl_xor(s, d, 64);
  float inv = rsqrtf(s);
  ushort4 r0, r1, n0, n1;
  r0.x = f2bf(a0.x); r0.y = f2bf(a0.y); r0.z = f2bf(a0.z); r0.w = f2bf(a0.w);
  r1.x = f2bf(a1.x); r1.y = f2bf(a1.y); r1.z = f2bf(a1.z); r1.w = f2bf(a1.w);
  n0.x = f2bf(a0.x*inv); n0.y = f2bf(a0.y*inv); n0.z = f2bf(a0.z*inv); n0.w = f2bf(a0.w*inv);
  n1.x = f2bf(a1.x*inv); n1.y = f2bf(a1.y*inv); n1.z = f2bf(a1.z*inv); n1.w = f2bf(a1.w*inv);
  ushort4* qr = (ushort4*)(yrbf + (size_t)row * Cn);
  ushort4* qn = (ushort4*)(ynbf + (size_t)row * Cn);
  qr[l] = r0; qr[64 + l] = r1;
  qn[l] = n0; qn[64 + l] = n1;
}

// ---------------- nu: argmax counts ----------------
__global__ __launch_bounds__(256) void k_nu(const float* __restrict__ sm, int* __restrict__ cnts) {
  int g = blockIdx.x * 256 + threadIdx.x;
  int b = g >> 12, p = g & 4095;
  const float* base = sm + (size_t)b * Mn * Nn;
  float best = base[p];
  int bi = 0;
  #pragma unroll 4
  for (int k = 1; k < Mn; k++) {
    float v = base[(size_t)k * Nn + p];
    if (v > best) { best = v; bi = k; }
  }
  __shared__ int lc[Mn];
  if (threadIdx.x < Mn) lc[threadIdx.x] = 0;
  __syncthreads();
  atomicAdd(&lc[bi], 1);
  __syncthreads();
  if (threadIdx.x < Mn) atomicAdd(&cnts[b * Mn + threadIdx.x], lc[threadIdx.x]);
}

// ---------------- W transpose -> bf16 : WT[n][k], k in [0,1024) ----------------
__global__ __launch_bounds__(256) void k_wt(const float* __restrict__ w, unsigned short* __restrict__ wt) {
  __shared__ float tile[32][33];
  int k0 = blockIdx.x * 32;
  int n0 = blockIdx.y * 32;
  int tx = threadIdx.x & 31, ty = threadIdx.x >> 5;
  #pragma unroll
  for (int i = 0; i < 4; i++) tile[ty + 8*i][tx] = w[(size_t)(k0 + ty + 8*i) * 512 + n0 + tx];
  __syncthreads();
  #pragma unroll
  for (int i = 0; i < 4; i++)
    wt[(size_t)(n0 + ty + 8*i) * 1024 + k0 + tx] = f2bf(tile[tx][ty + 8*i]);
}

// ---------------- Z^T = (y @ W_bot)^T, bf16, layout [b][n(512)][m(32)] ----------------
__global__ __launch_bounds__(256) void k_zt(const unsigned short* __restrict__ yraw,
                                            const unsigned short* __restrict__ wt,
                                            unsigned short* __restrict__ zt) {
  int wv = blockIdx.x * 4 + (threadIdx.x >> 6);
  int l = threadIdx.x & 63;
  int b = wv >> 6, rem = wv & 63, mt = rem >> 5, nt = rem & 31;
  int kg = l >> 4;
  const unsigned short* ap = yraw + ((size_t)(b * 32 + mt * 16 + (l & 15)) * 512 + kg * 8);
  const unsigned short* bp = wt + ((size_t)(nt * 16 + (l & 15)) * 1024 + 512 + kg * 8);
  f32x4 acc = {0.f, 0.f, 0.f, 0.f};
  #pragma unroll
  for (int ks = 0; ks < 16; ks++) {
    bf16x8 a = *(const bf16x8*)(ap + ks * 32);
    bf16x8 bb = *(const bf16x8*)(bp + ks * 32);
    acc = MFMA16(a, bb, acc);
  }
  int n = nt * 16 + (l & 15);
  #pragma unroll
  for (int r = 0; r < 4; r++) {
    int m = mt * 16 + kg * 4 + r;
    zt[((size_t)b * 512 + n) * 32 + m] = f2bf(acc[r]);
  }
}

// ---------------- K matrix: Kmat = exp(-20*(1 - xn.yn)), f32 row-major ----------------
__global__ __launch_bounds__(256) void k_cost(const unsigned short* __restrict__ xbf,
                                              const float* __restrict__ xinv,
                                              const unsigned short* __restrict__ ynbf,
                                              float* __restrict__ kmat) {
  int wv = blockIdx.x * 4 + (threadIdx.x >> 6);  // 0..4095 row-tiles of 16
  int l = threadIdx.x & 63;
  int r0 = wv * 16;
  int b = r0 >> 12;
  int kg = l >> 4;
  const unsigned short* ap = xbf + ((size_t)(r0 + (l & 15)) * 512 + kg * 8);
  const unsigned short* b0p = ynbf + ((size_t)(b * 32 + (l & 15)) * 512 + kg * 8);
  const unsigned short* b1p = ynbf + ((size_t)(b * 32 + 16 + (l & 15)) * 512 + kg * 8);
  f32x4 acc0 = {0.f, 0.f, 0.f, 0.f}, acc1 = {0.f, 0.f, 0.f, 0.f};
  #pragma unroll
  for (int ks = 0; ks < 16; ks++) {
    bf16x8 a = *(const bf16x8*)(ap + ks * 32);
    acc0 = MFMA16(a, *(const bf16x8*)(b0p + ks * 32), acc0);
    acc1 = MFMA16(a, *(const bf16x8*)(b1p + ks * 32), acc1);
  }
  int col = l & 15;
  #pragma unroll
  for (int r = 0; r < 4; r++) {
    int row = r0 + kg * 4 + r;
    float inv = xinv[row];
    kmat[(size_t)row * 32 + col]      = __expf(-20.f * (1.f - acc0[r] * inv));
    kmat[(size_t)row * 32 + col + 16] = __expf(-20.f * (1.f - acc1[r] * inv));
  }
}

// ---------------- Sinkhorn: 32 blocks (2 per batch, 2048 rows each) ----------------
// Round-3 proven config: kq[64]/thread, chunked cacc[16]x2 (live ~116, VGPR 92,
// zero spill). Per-iteration cross-block column-sum exchange via L2 atomics.
__global__ __launch_bounds__(512, 2) void k_sink1(const float* __restrict__ kmat,
                                                  const int* __restrict__ cnts,
                                                  float* __restrict__ verr,
                                                  float* __restrict__ vtrace,
                                                  int* __restrict__ gflag,
                                                  float* __restrict__ gpart) {
  int bid = blockIdx.x;
  int h = bid >> 4;        // row-half 0/1
  int b = bid & 15;        // batch
  int self = bid;
  int peer = (bid + 16) & 31;
  int t = threadIdx.x;     // 0..511
  int lane = t & 63;
  int w = t >> 6;          // wave 0..7
  __shared__ float v_s[32], nu_s[32];
  __shared__ float red_s[8];
  __shared__ float cred[8][32];
  __shared__ float vhist[50][32];
  __shared__ float ehist[50];
  __shared__ float errtot_s;
  if (t < 32) {
    float c = (float)cnts[b * 32 + t];
    float nu = c / (4096.f + 1e-8f) + 1e-6f;
    float ss = nu;
    #pragma unroll
    for (int d = 1; d < 32; d <<= 1) ss += __shfl_xor(ss, d, 64);
    nu_s[t] = nu / ss;
    v_s[t] = 0.f;
  }
  // one-time load of this thread's 4 rows of K, packed to bf16 pairs (64 VGPRs)
  unsigned kq[64];
  {
    const float4* kp = (const float4*)(kmat + ((size_t)b * 4096 + h * 2048 + (size_t)t * 4) * 32);
    #pragma unroll
    for (int r = 0; r < 4; r++) {
      #pragma unroll
      for (int q = 0; q < 8; q++) {
        float4 kv = kp[r * 8 + q];
        kq[r * 16 + q * 2]     = (unsigned)f2bf(kv.x) | ((unsigned)f2bf(kv.y) << 16);
        kq[r * 16 + q * 2 + 1] = (unsigned)f2bf(kv.z) | ((unsigned)f2bf(kv.w) << 16);
      }
    }
  }
  float uprev[4] = {0.f, 0.f, 0.f, 0.f};
  __syncthreads();

  for (int iter = 0; iter < 50; iter++) {
    // ---- u-pass: rows h*2048 + 4t .. +3, v broadcast from LDS ----
    float accA[4] = {0.f, 0.f, 0.f, 0.f}, accB[4] = {0.f, 0.f, 0.f, 0.f};
    {
      const float4* v4 = (const float4*)v_s;
      #pragma unroll
      for (int j = 0; j < 8; j++) {
        float4 vv = v4[j];
        #pragma unroll
        for (int hh = 0; hh < 2; hh++) {
          int q = j * 2 + hh;
          float va = hh ? vv.z : vv.x;
          float vb = hh ? vv.w : vv.y;
          #pragma unroll
          for (int r = 0; r < 4; r++) {
            unsigned pk = kq[r * 16 + q];
            accA[r] += bflo(pk) * va;
            accB[r] += bfhi(pk) * vb;
          }
        }
      }
    }
    float un[4];
    float errloc = 0.f;
    #pragma unroll
    for (int r = 0; r < 4; r++) {
      un[r] = (1.0f/4096.f) / (accA[r] + accB[r] + 1e-8f);
      errloc += fabsf(un[r] - uprev[r]);
      uprev[r] = un[r];
    }
    #pragma unroll
    for (int d = 1; d < 64; d <<= 1) errloc += __shfl_xor(errloc, d, 64);
    if (lane == 0) red_s[w] = errloc;

    // ---- v-pass partials, 2 chunks of 16 cols (keeps live regs low) ----
    #define FOLD(MASK, HALF)                                        \
    {                                                               \
      bool up_ = (lane & (MASK)) != 0;                              \
      _Pragma("unroll")                                             \
      for (int i = 0; i < (HALF); i++) {                            \
        float s_ = up_ ? cacc[i] : cacc[i + (HALF)];                \
        float r_ = __shfl_xor(s_, (MASK), 64);                      \
        cacc[i] = (up_ ? cacc[i + (HALF)] : cacc[i]) + r_;          \
      }                                                             \
    }
    #pragma unroll
    for (int ch = 0; ch < 2; ch++) {
      float cacc[16];
      #pragma unroll
      for (int c = 0; c < 16; c++) cacc[c] = 0.f;
      #pragma unroll
      for (int qq = 0; qq < 8; qq++) {
        int q = ch * 8 + qq;
        #pragma unroll
        for (int r = 0; r < 4; r++) {
          unsigned pk = kq[r * 16 + q];
          cacc[2*qq]   += bflo(pk) * un[r];
          cacc[2*qq+1] += bfhi(pk) * un[r];
        }
      }
      FOLD(1, 8)
      FOLD(2, 4)
      FOLD(4, 2)
      FOLD(8, 1)
      cacc[0] += __shfl_xor(cacc[0], 16, 64);
      cacc[0] += __shfl_xor(cacc[0], 32, 64);
      int col4 = ((lane & 1) << 3) | ((lane & 2) << 1) | ((lane & 4) >> 1) | ((lane & 8) >> 3);
      if (lane < 16) cred[w][ch * 16 + col4] = cacc[0];
    }
    #undef FOLD
    __syncthreads();  // A: cred/red_s ready

    // ---- wave 0: intra-block reduce + cross-block exchange + v update ----
    if (w == 0) {
      float sumP = 0.f, errP = 0.f;
      if (lane < 32) {
        #pragma unroll
        for (int ww = 0; ww < 8; ww++) sumP += cred[ww][lane];
      }
      if (lane == 0) {
        #pragma unroll
        for (int ww = 0; ww < 8; ww++) errP += red_s[ww];
      }
      int slotS = ((self << 1) | (iter & 1)) * 33;
      int slotP = ((peer << 1) | (iter & 1)) * 33;
      if (lane < 32)
        __hip_atomic_store(&gpart[slotS + lane], sumP, __ATOMIC_RELAXED, __HIP_MEMORY_SCOPE_AGENT);
      if (lane == 0) {
        __hip_atomic_store(&gpart[slotS + 32], errP, __ATOMIC_RELAXED, __HIP_MEMORY_SCOPE_AGENT);
        __hip_atomic_store(&gflag[self], iter + 1, __ATOMIC_RELEASE, __HIP_MEMORY_SCOPE_AGENT);
        while (__hip_atomic_load(&gflag[peer], __ATOMIC_ACQUIRE, __HIP_MEMORY_SCOPE_AGENT) < iter + 1)
          __builtin_amdgcn_s_sleep(1);
      }
      float part = 0.f, perr = 0.f;
      if (lane < 32)
        part = __hip_atomic_load(&gpart[slotP + lane], __ATOMIC_RELAXED, __HIP_MEMORY_SCOPE_AGENT);
      if (lane == 0)
        perr = __hip_atomic_load(&gpart[slotP + 32], __ATOMIC_RELAXED, __HIP_MEMORY_SCOPE_AGENT);
      float etot = __shfl(errP + perr, 0, 64);
      if (lane < 32) {
        float v = nu_s[lane] / (sumP + part + 1e-8f);
        v_s[lane] = v;
        if (h == 0) vhist[iter][lane] = v;
      }
      if (lane == 0) {
        errtot_s = etot;
        if (h == 0) ehist[iter] = etot;
      }
    }
    __syncthreads();  // B: v_s/errtot_s ready
    if (errtot_s == 0.0f) {
      // fp32 fixpoint: all further iterations identical — fill and stop
      if (h == 0 && t < 32) {
        float vv = v_s[t];
        for (int k = iter; k < 50; k++) vhist[k][t] = vv;
        if (t == 0) for (int k = iter; k < 50; k++) ehist[k] = 0.f;
      }
      break;
    }
  }

  // ---- dump histories to global (once, half-0 blocks only) ----
  if (h == 0) {
    __syncthreads();
    for (int idx = t; idx < 1600; idx += 512) {
      int k = idx >> 5, m = idx & 31;
      vtrace[k * 512 + b * 32 + m] = vhist[k][m];
    }
    if (t < 50) verr[t * 16 + b] = ehist[t];
  }
}

// ---------------- stop iteration: first iter with batch-mean err < 0.1 ----------------
__global__ void k_stop(const float* __restrict__ verr, int* __restrict__ jstar) {
  int t = threadIdx.x;
  float m = 1e30f;
  if (t < 50) {
    float s = 0.f;
    #pragma unroll
    for (int b2 = 0; b2 < 16; b2++) s += verr[t * 16 + b2];
    m = s * (1.f / 16.f);
  }
  unsigned long long mask = __ballot(m < 0.1f);
  if (t == 0) *jstar = mask ? (int)(__ffsll(mask) - 1) : 49;
}

// ---------------- pi, pi_norm (bf16), ot ----------------
__global__ __launch_bounds__(256) void k_pi(const float* __restrict__ kmat,
                                            const float* __restrict__ vtrace,
                                            const int* __restrict__ jstar,
                                            unsigned short* __restrict__ pinbf,
                                            float* __restrict__ piout,
                                            float* __restrict__ otout) {
  int gr = blockIdx.x * 256 + threadIdx.x;  // row 0..65535 (block never straddles a batch)
  int b = gr >> 12;
  __shared__ float vp_s[32], vc_s[32];
  __shared__ float red[4];
  if (threadIdx.x < 32) {
    int j = *jstar;
    vp_s[threadIdx.x] = (j == 0) ? 0.f : vtrace[(j - 1) * 512 + b * 32 + threadIdx.x];
    vc_s[threadIdx.x] = vtrace[j * 512 + b * 32 + threadIdx.x];
  }
  __syncthreads();
  const float4* kp = (const float4*)(kmat + (size_t)gr * 32);
  float4 K4[8];
  #pragma unroll
  for (int q = 0; q < 8; q++) K4[q] = kp[q];
  float qd = 0.f;
  #pragma unroll
  for (int q = 0; q < 8; q++)
    qd += K4[q].x * vp_s[q*4] + K4[q].y * vp_s[q*4+1] + K4[q].z * vp_s[q*4+2] + K4[q].w * vp_s[q*4+3];
  float u = (1.0f/4096.f) / (qd + 1e-8f);
  float pi[32];
  float s = 0.f, ot = 0.f;
  #pragma unroll
  for (int q = 0; q < 8; q++) {
    float kv[4] = {K4[q].x, K4[q].y, K4[q].z, K4[q].w};
    #pragma unroll
    for (int r = 0; r < 4; r++) {
      int m = q * 4 + r;
      float p = u * kv[r] * vc_s[m];
      pi[m] = p;
      s += p;
      ot += p * (-0.05f * __logf(kv[r]));
    }
  }
  float inv = 1.0f / (s + 1e-8f);
  float4* po = (float4*)(piout + (size_t)gr * 32);
  #pragma unroll
  for (int q = 0; q < 8; q++) {
    float4 w; w.x = pi[q*4]; w.y = pi[q*4+1]; w.z = pi[q*4+2]; w.w = pi[q*4+3];
    po[q] = w;
  }
  us8* pb = (us8*)(pinbf + (size_t)gr * 32);
  #pragma unroll
  for (int q = 0; q < 4; q++) {
    us8 v8;
    #pragma unroll
    for (int r = 0; r < 8; r++) v8[r] = f2bf(pi[q*8+r] * inv);
    pb[q] = v8;
  }
  #pragma unroll
  for (int d = 1; d < 64; d <<= 1) ot += __shfl_xor(ot, d, 64);
  if ((threadIdx.x & 63) == 0) red[threadIdx.x >> 6] = ot;
  __syncthreads();
  if (threadIdx.x == 0) atomicAdd(&otout[b], red[0] + red[1] + red[2] + red[3]);
}

// ---------------- Fusion GEMM + LN: out = LN(x@Wtop + pin@Z + bias) ----------------
// A-tile (64 rows x 32 k, shared by all 4 waves) staged via global_load_lds,
// double-buffered, one barrier per k-step. XOR swizzle slot s = kg ^ ((row>>1)&3)
// applied on BOTH sides (pre-swizzled global source + swizzled ds_read) -> 2-way
// bank aliasing (free). B panels stream from L2 as before.
__global__ __launch_bounds__(256, 2) void k_fusion(const unsigned short* __restrict__ xbf,
                                                   const unsigned short* __restrict__ pinbf,
                                                   const unsigned short* __restrict__ wt,
                                                   const unsigned short* __restrict__ zt,
                                                   const float* __restrict__ bias,
                                                   const float* __restrict__ gamma,
                                                   const float* __restrict__ beta_,
                                                   float* __restrict__ out) {
  int t = threadIdx.x;
  int wid = t >> 6, l = t & 63;
  int row0 = blockIdx.x * 64;
  int b = row0 >> 12;
  int col0 = wid * 128;
  int m16 = l & 15, kg = l >> 4;
  __shared__ __align__(16) unsigned short As[2][2048];  // 2 bufs x 64 rows x 32 bf16 (linear)
  f32x4 acc[4][8];
  #pragma unroll
  for (int rt = 0; rt < 4; rt++)
    #pragma unroll
    for (int ct = 0; ct < 8; ct++) acc[rt][ct] = (f32x4){0.f, 0.f, 0.f, 0.f};

  // staging geometry: thread t fills LDS bytes t*16 (row = t>>2, slot s = t&3);
  // content(row, s) = A[row0+row][ks*32 + (s ^ ((row>>1)&3))*8 .. +7]
  int srow = t >> 2, sslot = t & 3;
  int sswz = sslot ^ ((srow >> 1) & 3);
  const unsigned short* sbase = xbf + (size_t)(row0 + srow) * 512 + sswz * 8;

  const unsigned short* bB[8];
  #pragma unroll
  for (int ct = 0; ct < 8; ct++) bB[ct] = wt + ((size_t)(col0 + ct * 16 + m16) * 1024 + kg * 8);

  // read swizzle: row = rt*16+m16 -> (row>>1)&3 == (m16>>1)&3 (rt*16 contributes 0 mod 4)
  int rswz = kg ^ ((m16 >> 1) & 3);

  #define STAGE(buf, ks)                                                          \
    __builtin_amdgcn_global_load_lds(                                             \
        (const __attribute__((address_space(1))) unsigned int*)(sbase + (ks) * 32), \
        (__attribute__((address_space(3))) unsigned int*)&As[(buf)][(size_t)wid * 512], \
        16, 0, 0)

  STAGE(0, 0);
  __syncthreads();  // compiler drains vmcnt before barrier

  for (int ks = 0; ks < 16; ks++) {
    int cur = ks & 1;
    if (ks < 15) STAGE(cur ^ 1, ks + 1);
    bf16x8 A[4], Bf[8];
    #pragma unroll
    for (int rt = 0; rt < 4; rt++)
      A[rt] = *(const bf16x8*)&As[cur][(rt * 16 + m16) * 32 + rswz * 8];
    #pragma unroll
    for (int ct = 0; ct < 8; ct++) Bf[ct] = *(const bf16x8*)(bB[ct] + ks * 32);
    #pragma unroll
    for (int rt = 0; rt < 4; rt++)
      #pragma unroll
      for (int ct = 0; ct < 8; ct++) acc[rt][ct] = MFMA16(A[rt], Bf[ct], acc[rt][ct]);
    __syncthreads();  // staged ks+1 ready; all waves done with As[cur]
  }
  {  // pi_norm @ Z chunk (K=32)
    bf16x8 A[4], Bf[8];
    #pragma unroll
    for (int rt = 0; rt < 4; rt++)
      A[rt] = *(const bf16x8*)(pinbf + (size_t)(row0 + rt * 16 + m16) * 32 + kg * 8);
    #pragma unroll
    for (int ct = 0; ct < 8; ct++)
      Bf[ct] = *(const bf16x8*)(zt + ((size_t)(b * 512 + col0 + ct * 16 + m16)) * 32 + kg * 8);
    #pragma unroll
    for (int rt = 0; rt < 4; rt++)
      #pragma unroll
      for (int ct = 0; ct < 8; ct++) acc[rt][ct] = MFMA16(A[rt], Bf[ct], acc[rt][ct]);
  }
  float bi[8], ga[8], be[8];
  #pragma unroll
  for (int ct = 0; ct < 8; ct++) {
    int c = col0 + ct * 16 + m16;
    bi[ct] = bias[c]; ga[ct] = gamma[c]; be[ct] = beta_[c];
  }
  __shared__ float p1[4][64], p2[4][64];
  #pragma unroll
  for (int rt = 0; rt < 4; rt++) {
    #pragma unroll
    for (int r = 0; r < 4; r++) {
      float s1 = 0.f, s2 = 0.f;
      #pragma unroll
      for (int ct = 0; ct < 8; ct++) {
        float val = acc[rt][ct][r] + bi[ct];
        s1 += val; s2 += val * val;
      }
      #pragma unroll
      for (int d = 1; d < 16; d <<= 1) {
        s1 += __shfl_xor(s1, d, 64);
        s2 += __shfl_xor(s2, d, 64);
      }
      if (m16 == 0) {
        int rloc = rt * 16 + kg * 4 + r;
        p1[wid][rloc] = s1; p2[wid][rloc] = s2;
      }
    }
  }
  __syncthreads();
  __shared__ float lnM[64], lnR[64];
  if (t < 64) {
    float s1 = p1[0][t] + p1[1][t] + p1[2][t] + p1[3][t];
    float s2 = p2[0][t] + p2[1][t] + p2[2][t] + p2[3][t];
    float mean = s1 * (1.f / 512.f);
    float var = s2 * (1.f / 512.f) - mean * mean;
    lnM[t] = mean;
    lnR[t] = rsqrtf(var + 1e-5f);
  }
  __syncthreads();
  #pragma unroll
  for (int rt = 0; rt < 4; rt++) {
    #pragma unroll
    for (int r = 0; r < 4; r++) {
      int rloc = rt * 16 + kg * 4 + r;
      float mean = lnM[rloc], rst = lnR[rloc];
      #pragma unroll
      for (int ct = 0; ct < 8; ct++) {
        float val = acc[rt][ct][r] + bi[ct];
        out[(size_t)(row0 + rloc) * 512 + col0 + ct * 16 + m16] = (val - mean) * rst * ga[ct] + be[ct];
      }
    }
  }
}

extern "C" void kernel_launch(void* const* d_in, const int* in_sizes, int n_in,
                              void* d_out, int out_size, void* d_ws, size_t ws_size,
                              hipStream_t stream) {
  const float* x  = (const float*)d_in[0];
  const float* y  = (const float*)d_in[1];
  const float* sm = (const float*)d_in[2];
  const float* fw = (const float*)d_in[3];
  const float* fb = (const float*)d_in[4];
  const float* g  = (const float*)d_in[5];
  const float* be = (const float*)d_in[6];

  char* ws = (char*)d_ws;
  unsigned short* xbf   = (unsigned short*)(ws + OFF_XBF);
  float*          xinv  = (float*)(ws + OFF_XINV);
  unsigned short* ynbf  = (unsigned short*)(ws + OFF_YN);
  unsigned short* yrbf  = (unsigned short*)(ws + OFF_YR);
  unsigned short* wtbf  = (unsigned short*)(ws + OFF_WT);
  unsigned short* ztbf  = (unsigned short*)(ws + OFF_ZT);
  int*            cnts  = (int*)(ws + OFF_CNT);
  float*          verr  = (float*)(ws + OFF_VERR);
  int*            jst   = (int*)(ws + OFF_JS);
  float*          vtr   = (float*)(ws + OFF_VTR);
  float*          kmat  = (float*)(ws + OFF_K);
  unsigned short* pinbf = (unsigned short*)(ws + OFF_PIN);
  int*            gflag = (int*)(ws + OFF_PIN);          // aliases pinbf (disjoint lifetime)
  float*          gpart = (float*)(ws + OFF_PIN + 128);  // aliases pinbf (disjoint lifetime)

  float* outp = (float*)d_out;
  float* otp  = outp + (size_t)Bn * Nn * Cn;
  float* pip  = otp + Bn;

  hipLaunchKernelGGL(k_init, dim3(1), dim3(512), 0, stream, cnts, otp, gflag);
  hipLaunchKernelGGL(k_xprep, dim3(NR / 4), dim3(256), 0, stream, x, xbf, xinv);
  hipLaunchKernelGGL(k_ynorm, dim3(128), dim3(256), 0, stream, y, ynbf, yrbf);
  hipLaunchKernelGGL(k_nu, dim3(256), dim3(256), 0, stream, sm, cnts);
  hipLaunchKernelGGL(k_wt, dim3(32, 16), dim3(256), 0, stream, fw, wtbf);
  hipLaunchKernelGGL(k_zt, dim3(256), dim3(256), 0, stream, yrbf, wtbf, ztbf);
  hipLaunchKernelGGL(k_cost, dim3(1024), dim3(256), 0, stream, xbf, xinv, ynbf, kmat);
  hipLaunchKernelGGL(k_sink1, dim3(32), dim3(512), 0, stream, kmat, cnts, verr, vtr, gflag, gpart);
  hipLaunchKernelGGL(k_stop, dim3(1), dim3(64), 0, stream, verr, jst);
  hipLaunchKernelGGL(k_pi, dim3(256), dim3(256), 0, stream, kmat, vtr, jst, pinbf, pip, otp);
  hipLaunchKernelGGL(k_fusion, dim3(1024), dim3(256), 0, stream,
                     xbf, pinbf, wtbf, ztbf, fb, g, be, outp);
}